// Round 16
// baseline (47.525 us; speedup 1.0000x reference)
//
#include <hip/hip_runtime.h>
#include <math.h>

#define NNODES 4096
#define CC     128
#define EE     65536
#define MM     128

typedef __attribute__((ext_vector_type(8))) short short8;
typedef __attribute__((ext_vector_type(4))) float f32x4;

__device__ __forceinline__ float bf2f(ushort u) { return __uint_as_float(((unsigned)u) << 16); }
__device__ __forceinline__ ushort f2bf(float f) {
  unsigned b = __float_as_uint(f);
  return (ushort)((b + 0x7FFFu + ((b >> 16) & 1u)) >> 16);
}

// ===== prep: Wo/W1/W2 transposes (96) + e01 (16) + edge scatter (128, 1 edge/thread) =====
__global__ __launch_bounds__(512) void prep_kernel(const float* __restrict__ Wo,
                                                   const float* __restrict__ W1,
                                                   const float* __restrict__ W2,
                                                   const float* __restrict__ adj_emb,
                                                   const float* __restrict__ We,
                                                   const float* __restrict__ be,
                                                   const int* __restrict__ edge,
                                                   ushort* __restrict__ WoT,
                                                   ushort* __restrict__ W1T,
                                                   ushort* __restrict__ W2T,
                                                   float* __restrict__ e01,
                                                   unsigned* __restrict__ adjw) {
  __shared__ float lds[2][32][33];
  int b = blockIdx.x, t = threadIdx.x;
  if (b < 96) {
    int sub = t >> 8, tt = t & 255;
    int tid = b * 2 + sub;
    const float* src; ushort* dst; int N, K, tile;
    if (tid < 64)       { src = Wo; dst = WoT; N = 128; K = 512; tile = tid; }
    else if (tid < 128) { src = W1; dst = W1T; N = 512; K = 128; tile = tid - 64; }
    else                { src = W2; dst = W2T; N = 128; K = 512; tile = tid - 128; }
    int tilesN = N >> 5;
    int k0 = (tile / tilesN) << 5, n0 = (tile % tilesN) << 5;
#pragma unroll
    for (int i = 0; i < 4; ++i) {
      int idx = i * 256 + tt, kk = idx >> 5, nn = idx & 31;
      lds[sub][kk][nn] = src[(size_t)(k0 + kk) * N + n0 + nn];
    }
    __syncthreads();
#pragma unroll
    for (int i = 0; i < 4; ++i) {
      int idx = i * 256 + tt, nn = idx >> 5, kk = idx & 31;
      dst[(size_t)(n0 + nn) * K + k0 + kk] = f2bf(lds[sub][kk][nn]);
    }
  } else if (b < 112) {
    int gidx = (b - 96) * 512 + t;   // 0..8191
    int o = gidx >> 3, part = gidx & 7;
    int which = o >> 9, col = o & 511;
    int c0 = part * 16;
    float a = 0.f;
#pragma unroll
    for (int cc = 0; cc < 16; ++cc)
      a += adj_emb[which * CC + c0 + cc] * We[(size_t)(c0 + cc) * 512 + col];
    a += __shfl_xor(a, 1); a += __shfl_xor(a, 2); a += __shfl_xor(a, 4);
    if (part == 0) e01[o] = a + be[col];
  } else {
    int e = (b - 112) * 512 + t;
    int s = edge[e], d = edge[EE + e];
    int cs = s >> 7, cd = d >> 7;
    if (cs == cd) {
      int flat = cs * (MM * MM) + (s & 127) * MM + (d & 127);
      atomicOr(adjw + (flat >> 5), 1u << (flat & 31));
    }
  }
}

// ===== fused LN1 + QKV GEMM (BK=64 x2) + rotary + attention; 52KB LDS, 3 blocks/CU ====
#define ATT_SMEM 53248
__global__ __launch_bounds__(512) void attn_kernel(const float* __restrict__ x,
                                                   const int* __restrict__ cl,
                                                   const float* __restrict__ ln1g,
                                                   const float* __restrict__ ln1b,
                                                   const float* __restrict__ Wq,
                                                   const float* __restrict__ bq,
                                                   const float* __restrict__ Wkv,
                                                   const float* __restrict__ bkv,
                                                   const unsigned* __restrict__ adjw,
                                                   const float* __restrict__ e01,
                                                   ushort* __restrict__ AO) {
  __shared__ __align__(16) char SM[ATT_SMEM];
  ushort* Ab = (ushort*)SM;             // [128][64] per K-pass (16 KB)
  ushort* Bb = (ushort*)(SM + 16384);   // [192][64] per K-pass (24 KB)
  ushort* Qb = (ushort*)SM;             // [128][64] attn overlay
  ushort* Kb = (ushort*)(SM + 16384);   // [128][64]
  ushort* VT = (ushort*)(SM + 32768);   // [64][128]
  ushort* Pl = (ushort*)SM;             // [2][64][128] overlays Qb+Kb (after barrier)
  float* gb  = (float*)(SM + 49152);    // 256 floats; adjL overlays later
  unsigned* adjL = (unsigned*)(SM + 49152);  // 512 words
  float* e0s  = (float*)(SM + 51200);
  float* e1s  = (float*)(SM + 51456);
  float* qe0L = (float*)(SM + 51712);   // [128]
  float* qe1L = (float*)(SM + 52224);   // [128]
  float* sL   = (float*)(SM + 52736);   // [128]

  int b = blockIdx.x, t = threadIdx.x;
  int kc = b >> 3, h = b & 7;
  int w = t >> 6, l = t & 63;

  if (t < 128) gb[t] = ln1g[t];
  else if (t < 256) gb[t] = ln1b[t - 128];

  // ---- LN1 stats (once): 4 threads/row, xv kept in registers ----
  int arow_ = t >> 2, apart = t & 3;
  float xv[32];
  float mu, rs;
  {
    int srcn = cl[kc * 128 + arow_];
    const float* xr = x + (size_t)srcn * CC + apart * 32;
#pragma unroll
    for (int i = 0; i < 8; ++i) {
      float4 v4 = *(const float4*)(xr + i * 4);
      xv[i * 4 + 0] = v4.x; xv[i * 4 + 1] = v4.y; xv[i * 4 + 2] = v4.z; xv[i * 4 + 3] = v4.w;
    }
    float s = 0.f, q = 0.f;
#pragma unroll
    for (int j = 0; j < 32; ++j) { s += xv[j]; q += xv[j] * xv[j]; }
    s += __shfl_xor(s, 1); q += __shfl_xor(q, 1);
    s += __shfl_xor(s, 2); q += __shfl_xor(q, 2);
    mu = s * (1.0f / CC);
    rs = rsqrtf(q * (1.0f / CC) - mu * mu + 1e-5f);
  }
  __syncthreads();  // gb ready

  // ---- QKV GEMM: two BK=64 passes ----
  f32x4 acc[12];
#pragma unroll
  for (int nj = 0; nj < 12; ++nj) acc[nj] = (f32x4){0.f, 0.f, 0.f, 0.f};
  for (int kp = 0; kp < 2; ++kp) {
    if (t < 384) {  // B half-stage: [192][64]
      int nl = t >> 1, kh = t & 1;
      const float* bsrc; int Nw, coln;
      if (nl < 64)       { bsrc = Wq;  Nw = 512;  coln = h * 64 + nl; }
      else if (nl < 128) { bsrc = Wkv; Nw = 1024; coln = h * 64 + (nl - 64); }
      else               { bsrc = Wkv; Nw = 1024; coln = 512 + h * 64 + (nl - 128); }
#pragma unroll
      for (int kcc = 0; kcc < 4; ++kcc) {
        float vals[8];
#pragma unroll
        for (int e = 0; e < 8; ++e)
          vals[e] = bsrc[(size_t)(kp * 64 + kh * 32 + kcc * 8 + e) * Nw + coln];
        int chl = kh * 4 + kcc;
        uint4 pk;
        pk.x = (unsigned)f2bf(vals[0]) | ((unsigned)f2bf(vals[1]) << 16);
        pk.y = (unsigned)f2bf(vals[2]) | ((unsigned)f2bf(vals[3]) << 16);
        pk.z = (unsigned)f2bf(vals[4]) | ((unsigned)f2bf(vals[5]) << 16);
        pk.w = (unsigned)f2bf(vals[6]) | ((unsigned)f2bf(vals[7]) << 16);
        *(uint4*)&Bb[nl * 64 + ((chl ^ (nl & 7)) << 3)] = pk;
      }
    }
    if ((apart >> 1) == kp) {  // A half-stage: cols kp*64..+63 (parts 2kp, 2kp+1)
#pragma unroll
      for (int cc = 0; cc < 4; ++cc) {
        ushort pk8[8];
#pragma unroll
        for (int e = 0; e < 8; ++e) {
          int c = apart * 32 + cc * 8 + e;
          pk8[e] = f2bf((xv[cc * 8 + e] - mu) * rs * gb[c] + gb[128 + c]);
        }
        int chl = (apart & 1) * 4 + cc;
        uint4 pk;
        pk.x = (unsigned)pk8[0] | ((unsigned)pk8[1] << 16);
        pk.y = (unsigned)pk8[2] | ((unsigned)pk8[3] << 16);
        pk.z = (unsigned)pk8[4] | ((unsigned)pk8[5] << 16);
        pk.w = (unsigned)pk8[6] | ((unsigned)pk8[7] << 16);
        *(uint4*)&Ab[arow_ * 64 + ((chl ^ (arow_ & 7)) << 3)] = pk;
      }
    }
    __syncthreads();
#pragma unroll
    for (int kk = 0; kk < 2; ++kk) {
      int gch = kk * 4 + (l >> 4);
      int arow = w * 16 + (l & 15);
      short8 aF = *(const short8*)&Ab[arow * 64 + ((gch ^ (arow & 7)) << 3)];
#pragma unroll
      for (int nj = 0; nj < 12; ++nj) {
        int brow = nj * 16 + (l & 15);
        short8 bF = *(const short8*)&Bb[brow * 64 + ((gch ^ (brow & 7)) << 3)];
        acc[nj] = __builtin_amdgcn_mfma_f32_16x16x32_bf16(aF, bF, acc[nj], 0, 0, 0);
      }
    }
    __syncthreads();
  }

  // ---- epilogue: bias + rotary (Q,K) -> Qb/Kb ; bias -> VT ----
  {
    int mb = w * 16 + ((l >> 4) << 2);
#pragma unroll
    for (int nj = 0; nj < 8; ++nj) {
      int n = nj * 16 + (l & 15);
      int d = n & 63;
      float bias = (nj < 4) ? bq[h * 64 + d] : bkv[h * 64 + d];
      float invv = exp2f(-(float)(d >> 1) * 0.4152410118609203f);  // 10000^(-p/32)
      int ch = d >> 3;
#pragma unroll
      for (int r = 0; r < 4; ++r) {
        int m = mb + r;
        float v = acc[nj][r] + bias;
        float praw = __shfl_xor(v, 1);
        float sn, cn;
        __sincosf((float)m * invv, &sn, &cn);
        float vr = (n & 1) ? (v * cn + praw * sn) : (v * cn - praw * sn);
        ushort uv = f2bf(vr);
        if (nj < 4) Qb[m * 64 + ((ch ^ (m & 7)) << 3) + (d & 7)] = uv;
        else        Kb[m * 64 + ((ch ^ (m & 7)) << 3) + (d & 7)] = uv;
      }
    }
#pragma unroll
    for (int nj = 8; nj < 12; ++nj) {
      int n = nj * 16 + (l & 15);
      int d = n - 128;
      float bias = bkv[512 + h * 64 + d];
#pragma unroll
      for (int r = 0; r < 4; ++r) {
        int m = mb + r;
        VT[d * 128 + (((m >> 3) ^ (d & 7)) << 3) + (m & 7)] = f2bf(acc[nj][r] + bias);
      }
    }
  }
  adjL[t & 511] = adjw[kc * 512 + (t & 511)];     // overlays dead gb (post-barrier region)
  if (t < 64) { e0s[t] = e01[h * 64 + t]; e1s[t] = e01[512 + h * 64 + t]; }
  __syncthreads();

  // ---- attention: two 256-thread half-units ----
  int sub = t >> 8, tt = t & 255;
  int q0 = sub * 64;
  int lw = tt >> 6;
  ushort* Plh = Pl + sub * 8192;

  {
    int row = tt >> 2, part = tt & 3;
    int gq = q0 + row;
    float a0 = 0.f, a1v = 0.f;
#pragma unroll
    for (int dd = 0; dd < 16; ++dd) {
      int d = part * 16 + dd;
      float qv = bf2f(Qb[gq * 64 + (((d >> 3) ^ (gq & 7)) << 3) + (d & 7)]);
      a0 += qv * e0s[d]; a1v += qv * e1s[d];
    }
    a0 += __shfl_xor(a0, 1); a0 += __shfl_xor(a0, 2);
    a1v += __shfl_xor(a1v, 1); a1v += __shfl_xor(a1v, 2);
    if (part == 0) { qe0L[gq] = a0; qe1L[gq] = a1v; }
  }

  int m0a = lw * 16;
  f32x4 s_acc[8];
#pragma unroll
  for (int nj = 0; nj < 8; ++nj) s_acc[nj] = (f32x4){0.f, 0.f, 0.f, 0.f};
  {
    int arow = q0 + m0a + (l & 15);
    short8 aF0 = *(const short8*)&Qb[arow * 64 + ((((l >> 4)) ^ (arow & 7)) << 3)];
    short8 aF1 = *(const short8*)&Qb[arow * 64 + (((4 + (l >> 4)) ^ (arow & 7)) << 3)];
#pragma unroll
    for (int nj = 0; nj < 8; ++nj) {
      int brow = nj * 16 + (l & 15);
      short8 b0 = *(const short8*)&Kb[brow * 64 + ((((l >> 4)) ^ (brow & 7)) << 3)];
      short8 b1v = *(const short8*)&Kb[brow * 64 + (((4 + (l >> 4)) ^ (brow & 7)) << 3)];
      s_acc[nj] = __builtin_amdgcn_mfma_f32_16x16x32_bf16(aF0, b0, s_acc[nj], 0, 0, 0);
      s_acc[nj] = __builtin_amdgcn_mfma_f32_16x16x32_bf16(aF1, b1v, s_acc[nj], 0, 0, 0);
    }
  }

  float mrow[4], ssum[4], sadj[4];
#pragma unroll
  for (int r = 0; r < 4; ++r) {
    int i = m0a + ((l >> 4) << 2) + r;
    int gi = q0 + i;
    float q0v = qe0L[gi], q1v = qe1L[gi];
    unsigned w0 = adjL[gi * 4 + 0], w1 = adjL[gi * 4 + 1], w2 = adjL[gi * 4 + 2], w3 = adjL[gi * 4 + 3];
    float mx = -1e30f;
#pragma unroll
    for (int nj = 0; nj < 8; ++nj) {
      unsigned word = (nj >> 1) == 0 ? w0 : (nj >> 1) == 1 ? w1 : (nj >> 1) == 2 ? w2 : w3;
      unsigned bit = (word >> (((nj & 1) << 4) + (l & 15))) & 1u;
      float s = (s_acc[nj][r] + (bit ? q1v : q0v)) * 0.125f;
      s_acc[nj][r] = s;
      mx = fmaxf(mx, s);
    }
    mrow[r] = mx;
  }
#pragma unroll
  for (int o = 1; o < 16; o <<= 1)
#pragma unroll
    for (int r = 0; r < 4; ++r) mrow[r] = fmaxf(mrow[r], __shfl_xor(mrow[r], o));
#pragma unroll
  for (int r = 0; r < 4; ++r) {
    float sum = 0.f;
#pragma unroll
    for (int nj = 0; nj < 8; ++nj) {
      float pv = __expf(s_acc[nj][r] - mrow[r]);
      s_acc[nj][r] = pv;
      sum += pv;
    }
    ssum[r] = sum;
  }
#pragma unroll
  for (int o = 1; o < 16; o <<= 1)
#pragma unroll
    for (int r = 0; r < 4; ++r) ssum[r] += __shfl_xor(ssum[r], o);
#pragma unroll
  for (int r = 0; r < 4; ++r) {
    int gi = q0 + m0a + ((l >> 4) << 2) + r;
    unsigned w0 = adjL[gi * 4 + 0], w1 = adjL[gi * 4 + 1], w2 = adjL[gi * 4 + 2], w3 = adjL[gi * 4 + 3];
    float inv = 1.0f / ssum[r];
    float sa = 0.f;
#pragma unroll
    for (int nj = 0; nj < 8; ++nj) {
      unsigned word = (nj >> 1) == 0 ? w0 : (nj >> 1) == 1 ? w1 : (nj >> 1) == 2 ? w2 : w3;
      unsigned bit = (word >> (((nj & 1) << 4) + (l & 15))) & 1u;
      float pv = s_acc[nj][r] * inv;
      s_acc[nj][r] = pv;
      if (bit) sa += pv;
    }
    sadj[r] = sa;
  }
#pragma unroll
  for (int o = 1; o < 16; o <<= 1)
#pragma unroll
    for (int r = 0; r < 4; ++r) sadj[r] += __shfl_xor(sadj[r], o);

  __syncthreads();  // all QK^T/qe reads of Qb/Kb complete -> safe to overlay Pl

#pragma unroll
  for (int r = 0; r < 4; ++r) {
    int i = m0a + ((l >> 4) << 2) + r;
#pragma unroll
    for (int nj = 0; nj < 8; ++nj) {
      int j = nj * 16 + (l & 15);
      Plh[i * 128 + (((j >> 3) ^ (i & 7)) << 3) + (j & 7)] = f2bf(s_acc[nj][r]);
    }
    if ((l & 15) == 0) sL[q0 + i] = sadj[r];
  }
  // (no barrier: PV reads only this wave's Plh/sL rows)

  f32x4 o_acc[4];
#pragma unroll
  for (int nj = 0; nj < 4; ++nj) o_acc[nj] = (f32x4){0.f, 0.f, 0.f, 0.f};
#pragma unroll
  for (int kk = 0; kk < 4; ++kk) {
    int prow = m0a + (l & 15);
    int ch = kk * 4 + (l >> 4);
    short8 pa = *(const short8*)&Plh[prow * 128 + ((ch ^ (prow & 7)) << 3)];
#pragma unroll
    for (int nj = 0; nj < 4; ++nj) {
      int vrow = nj * 16 + (l & 15);
      short8 vf = *(const short8*)&VT[vrow * 128 + ((ch ^ (vrow & 7)) << 3)];
      o_acc[nj] = __builtin_amdgcn_mfma_f32_16x16x32_bf16(pa, vf, o_acc[nj], 0, 0, 0);
    }
  }
#pragma unroll
  for (int nj = 0; nj < 4; ++nj)
#pragma unroll
    for (int r = 0; r < 4; ++r) {
      int i = m0a + ((l >> 4) << 2) + r;
      int d = nj * 16 + (l & 15);
      float s = sL[q0 + i];
      float v = o_acc[nj][r] + e0s[d] * (1.0f - s) + e1s[d] * s;
      float pv = __shfl_xor(v, 1);
      if ((l & 1) == 0) {
        unsigned pack = (unsigned)f2bf(v) | ((unsigned)f2bf(pv) << 16);
        *(unsigned*)&AO[(size_t)(kc * 128 + q0 + i) * 512 + h * 64 + d] = pack;
      }
    }
}

// ===== fused tail: 256 blocks x 16 rows, 512 threads; single-buffer Bb, 2 blocks/CU =====
__global__ __launch_bounds__(512) void tail_kernel(const ushort* __restrict__ AO,
                                                   const ushort* __restrict__ WoT,
                                                   const float* __restrict__ bo,
                                                   const ushort* __restrict__ W1T,
                                                   const float* __restrict__ b1,
                                                   const ushort* __restrict__ W2T,
                                                   const float* __restrict__ b2,
                                                   const float* __restrict__ x,
                                                   const int* __restrict__ cl,
                                                   const float* __restrict__ g1,
                                                   const float* __restrict__ g2,
                                                   const float* __restrict__ ln2g,
                                                   const float* __restrict__ ln2b,
                                                   float* __restrict__ out) {
  __shared__ __align__(16) char SM[64768];
  ushort* As = (ushort*)SM;                       // 16 KB
  ushort* Bb = (ushort*)(SM + 16384);             // 32 KB (single buffer)
  float (*tld)[132] = (float(*)[132])(SM + 49152);// 8448 B
  ushort* y2L = (ushort*)(SM + 57600);            // 4 KB
  float* w0g1 = (float*)(SM + 61696);             // 6*128*4 = 3072 B
  float* w1g1 = w0g1 + 128; float* w0g2 = w0g1 + 256; float* w1g2 = w0g1 + 384;
  float* lnG = w0g1 + 512; float* lnB = w0g1 + 640;

  int b = blockIdx.x, t = threadIdx.x;
  int m0t = b * 16;
  int w = t >> 6, l = t & 63;

  if (t < 128) { w0g1[t] = g1[t] + g1[256 + t]; w1g1[t] = g1[128 + t] - g1[256 + t]; }
  else if (t < 256) { int i = t - 128; w0g2[i] = g2[i] + g2[256 + i]; w1g2[i] = g2[128 + i] - g2[256 + i]; }
  else if (t < 384) { int i = t - 256; lnG[i] = ln2g[i]; lnB[i] = ln2b[i]; }
#pragma unroll
  for (int i = 0; i < 2; ++i) {
    int c = t + i * 512;
    int r = c >> 6, ch = c & 63;
    *(uint4*)&As[r * 512 + (((ch & ~7) | ((ch ^ r) & 7)) << 3)] =
        *(const uint4*)&AO[(size_t)(m0t + r) * 512 + ch * 8];
  }
  auto stage = [&](int s) {
#pragma unroll
    for (int i = 0; i < 4; ++i) {
      int c = t + i * 512;
      int r = c >> 4, kc = c & 15;
      const ushort* pp;
      if (s < 4)      pp = &WoT[(size_t)r * 512 + s * 128 + kc * 8];
      else if (s < 8) pp = &W1T[(size_t)((s - 4) * 128 + r) * 128 + kc * 8];
      else            pp = &W2T[(size_t)r * 512 + (s - 8) * 128 + kc * 8];
      *(uint4*)&Bb[r * 128 + (((kc & 8) | ((kc ^ r) & 7)) << 3)] = *(const uint4*)pp;
    }
  };

  int arow = l & 15;
  int brow = w * 16 + (l & 15);

  // ---- Wo: 4 single-buffered stages ----
  f32x4 aWo = (f32x4){0.f, 0.f, 0.f, 0.f};
  for (int s = 0; s < 4; ++s) {
    stage(s);
    __syncthreads();
#pragma unroll
    for (int kk = 0; kk < 4; ++kk) {
      int gA = s * 16 + kk * 4 + (l >> 4);
      short8 aF = *(const short8*)&As[arow * 512 + (((gA & ~7) | ((gA ^ arow) & 7)) << 3)];
      int gB = kk * 4 + (l >> 4);
      short8 bF = *(const short8*)&Bb[brow * 128 + (((gB & 8) | ((gB ^ brow) & 7)) << 3)];
      aWo = __builtin_amdgcn_mfma_f32_16x16x32_bf16(aF, bF, aWo, 0, 0, 0);
    }
    __syncthreads();
  }
#pragma unroll
  for (int r = 0; r < 4; ++r)
    tld[((l >> 4) << 2) + r][w * 16 + (l & 15)] = aWo[r] + bo[w * 16 + (l & 15)];
  __syncthreads();

  // ---- gate1 + LN2 ----
  int row = t >> 5, part = t & 31;
  int srcn = cl[m0t + row];
  float xv[4], n1r[4];
  {
    float4 x4 = *(const float4*)(x + (size_t)srcn * CC + part * 4);
    xv[0] = x4.x; xv[1] = x4.y; xv[2] = x4.z; xv[3] = x4.w;
    float dot = 0.f;
#pragma unroll
    for (int j = 0; j < 4; ++j) { int c = part * 4 + j; dot += tld[row][c] * w0g1[c] + xv[j] * w1g1[c]; }
#pragma unroll
    for (int o = 1; o < 32; o <<= 1) dot += __shfl_xor(dot, o);
    float g = 1.0f / (1.0f + __expf(-dot));
    float s = 0.f, q = 0.f;
#pragma unroll
    for (int j = 0; j < 4; ++j) {
      int c = part * 4 + j;
      float nv = tld[row][c] * g + xv[j] * (1.0f - g);
      n1r[j] = nv; s += nv; q += nv * nv;
    }
#pragma unroll
    for (int o = 1; o < 32; o <<= 1) { s += __shfl_xor(s, o); q += __shfl_xor(q, o); }
    float mu = s * (1.0f / CC);
    float rs = rsqrtf(q * (1.0f / CC) - mu * mu + 1e-5f);
    ushort pk2[4];
#pragma unroll
    for (int j = 0; j < 4; ++j) { int c = part * 4 + j; pk2[j] = f2bf((n1r[j] - mu) * rs * lnG[c] + lnB[c]); }
    int ch = part >> 1;
    int off = (((ch & 8) | ((ch ^ row) & 7)) << 3) + (part & 1) * 4;
    uint2 u2;
    u2.x = (unsigned)pk2[0] | ((unsigned)pk2[1] << 16);
    u2.y = (unsigned)pk2[2] | ((unsigned)pk2[3] << 16);
    *(uint2*)&y2L[row * 128 + off] = u2;
  }
  __syncthreads();

  // ---- W1 + GELU: 4 single-buffered stages; outputs overlay As ----
  for (int s = 4; s < 8; ++s) {
    stage(s);
    __syncthreads();
    f32x4 a1 = (f32x4){0.f, 0.f, 0.f, 0.f};
#pragma unroll
    for (int kk = 0; kk < 4; ++kk) {
      int gch = kk * 4 + (l >> 4);
      short8 aF = *(const short8*)&y2L[arow * 128 + (((gch & 8) | ((gch ^ arow) & 7)) << 3)];
      short8 bF = *(const short8*)&Bb[brow * 128 + (((gch & 8) | ((gch ^ brow) & 7)) << 3)];
      a1 = __builtin_amdgcn_mfma_f32_16x16x32_bf16(aF, bF, a1, 0, 0, 0);
    }
#pragma unroll
    for (int r = 0; r < 4; ++r) {
      int rw = ((l >> 4) << 2) + r;
      int n = (s - 4) * 128 + w * 16 + (l & 15);
      float v = a1[r] + b1[n];
      v = 0.5f * v * (1.0f + erff(v * 0.70710678118654752f));
      int ch = n >> 3;
      As[rw * 512 + (((ch & ~7) | ((ch ^ rw) & 7)) << 3) + (n & 7)] = f2bf(v);
    }
    __syncthreads();
  }

  // ---- W2: 4 single-buffered stages ----
  f32x4 a2 = (f32x4){0.f, 0.f, 0.f, 0.f};
  for (int s = 8; s < 12; ++s) {
    stage(s);
    __syncthreads();
#pragma unroll
    for (int kk = 0; kk < 4; ++kk) {
      int gA = (s - 8) * 16 + kk * 4 + (l >> 4);
      short8 aF = *(const short8*)&As[arow * 512 + (((gA & ~7) | ((gA ^ arow) & 7)) << 3)];
      int gB = kk * 4 + (l >> 4);
      short8 bF = *(const short8*)&Bb[brow * 128 + (((gB & 8) | ((gB ^ brow) & 7)) << 3)];
      a2 = __builtin_amdgcn_mfma_f32_16x16x32_bf16(aF, bF, a2, 0, 0, 0);
    }
    __syncthreads();
  }
#pragma unroll
  for (int r = 0; r < 4; ++r)
    tld[((l >> 4) << 2) + r][w * 16 + (l & 15)] = a2[r] + b2[w * 16 + (l & 15)];
  __syncthreads();

  // ---- gate2 + final add ----
  {
    float dot = 0.f;
#pragma unroll
    for (int j = 0; j < 4; ++j) { int c = part * 4 + j; dot += tld[row][c] * w0g2[c] + n1r[j] * w1g2[c]; }
#pragma unroll
    for (int o = 1; o < 32; o <<= 1) dot += __shfl_xor(dot, o);
    float g = 1.0f / (1.0f + __expf(-dot));
    float4 o4;
    float* op4 = (float*)&o4;
#pragma unroll
    for (int j = 0; j < 4; ++j) {
      int c = part * 4 + j;
      op4[j] = xv[j] + tld[row][c] * g + n1r[j] * (1.0f - g);
    }
    *(float4*)(out + (size_t)srcn * CC + part * 4) = o4;
  }
}

extern "C" void kernel_launch(void* const* d_in, const int* in_sizes, int n_in,
                              void* d_out, int out_size, void* d_ws, size_t ws_size,
                              hipStream_t stream) {
  const float* x       = (const float*)d_in[0];
  const int*   edge    = (const int*)d_in[1];
  const int*   clusters= (const int*)d_in[2];
  const float* adj_emb = (const float*)d_in[3];
  const float* ln1_g   = (const float*)d_in[4];
  const float* ln1_b   = (const float*)d_in[5];
  const float* Wq      = (const float*)d_in[6];
  const float* bq      = (const float*)d_in[7];
  const float* Wkv     = (const float*)d_in[8];
  const float* bkv     = (const float*)d_in[9];
  const float* We      = (const float*)d_in[10];
  const float* be      = (const float*)d_in[11];
  const float* Wo      = (const float*)d_in[12];
  const float* bo      = (const float*)d_in[13];
  const float* gate1   = (const float*)d_in[14];
  const float* ln2_g   = (const float*)d_in[15];
  const float* ln2_b   = (const float*)d_in[16];
  const float* W1      = (const float*)d_in[17];
  const float* b1      = (const float*)d_in[18];
  const float* W2      = (const float*)d_in[19];
  const float* b2      = (const float*)d_in[20];
  const float* gate2   = (const float*)d_in[21];

  char* wsb = (char*)d_ws;
  float* e01  = (float*)wsb;                         // 4 KB
  unsigned* adjw = (unsigned*)(wsb + 4096);          // 64 KB (zeroed by memset)
  ushort* WoT = (ushort*)(wsb + 69632);              // 128 KB
  ushort* W1T = (ushort*)(wsb + 200704);             // 128 KB
  ushort* W2T = (ushort*)(wsb + 331776);             // 128 KB
  ushort* AO  = (ushort*)(wsb + 462848);             // 4 MB

  hipMemsetAsync(adjw, 0, 65536, stream);
  prep_kernel<<<240, 512, 0, stream>>>(Wo, W1, W2, adj_emb, We, be, edge,
                                       WoT, W1T, W2T, e01, adjw);
  attn_kernel<<<256, 512, 0, stream>>>(x, clusters, ln1_g, ln1_b, Wq, bq, Wkv, bkv,
                                       adjw, e01, AO);
  tail_kernel<<<256, 512, 0, stream>>>(AO, WoT, bo, W1T, b1, W2T, b2,
                                       x, clusters, gate1, gate2, ln2_g, ln2_b, (float*)d_out);
}

// Round 17
// 40.685 us; speedup vs baseline: 1.1681x; 1.1681x over previous
//
#include <hip/hip_runtime.h>
#include <math.h>

#define NNODES 4096
#define CC     128
#define EE     65536
#define MM     128

typedef __attribute__((ext_vector_type(8))) short short8;
typedef __attribute__((ext_vector_type(4))) float f32x4;

__device__ __forceinline__ float bf2f(ushort u) { return __uint_as_float(((unsigned)u) << 16); }
__device__ __forceinline__ ushort f2bf(float f) {
  unsigned b = __float_as_uint(f);
  return (ushort)((b + 0x7FFFu + ((b >> 16) & 1u)) >> 16);
}

// ===== prep: Wo/W1/W2 transposes (96) + e01 (16) + quarter-mask edge scatter (128) =====
// scatter block (kc,part): LDS mask over edge quarter -> plain-store its own slice.
// No global pre-zero needed (every word of adjw4 fully overwritten each launch).
__global__ __launch_bounds__(512) void prep_kernel(const float* __restrict__ Wo,
                                                   const float* __restrict__ W1,
                                                   const float* __restrict__ W2,
                                                   const float* __restrict__ adj_emb,
                                                   const float* __restrict__ We,
                                                   const float* __restrict__ be,
                                                   const int* __restrict__ edge,
                                                   ushort* __restrict__ WoT,
                                                   ushort* __restrict__ W1T,
                                                   ushort* __restrict__ W2T,
                                                   float* __restrict__ e01,
                                                   unsigned* __restrict__ adjw4) {
  __shared__ float lds[2][32][33];
  __shared__ unsigned adjm[512];
  int b = blockIdx.x, t = threadIdx.x;
  if (b < 96) {
    int sub = t >> 8, tt = t & 255;
    int tid = b * 2 + sub;
    const float* src; ushort* dst; int N, K, tile;
    if (tid < 64)       { src = Wo; dst = WoT; N = 128; K = 512; tile = tid; }
    else if (tid < 128) { src = W1; dst = W1T; N = 512; K = 128; tile = tid - 64; }
    else                { src = W2; dst = W2T; N = 128; K = 512; tile = tid - 128; }
    int tilesN = N >> 5;
    int k0 = (tile / tilesN) << 5, n0 = (tile % tilesN) << 5;
#pragma unroll
    for (int i = 0; i < 4; ++i) {
      int idx = i * 256 + tt, kk = idx >> 5, nn = idx & 31;
      lds[sub][kk][nn] = src[(size_t)(k0 + kk) * N + n0 + nn];
    }
    __syncthreads();
#pragma unroll
    for (int i = 0; i < 4; ++i) {
      int idx = i * 256 + tt, nn = idx >> 5, kk = idx & 31;
      dst[(size_t)(n0 + nn) * K + k0 + kk] = f2bf(lds[sub][kk][nn]);
    }
  } else if (b < 112) {
    int gidx = (b - 96) * 512 + t;   // 0..8191
    int o = gidx >> 3, part = gidx & 7;
    int which = o >> 9, col = o & 511;
    int c0 = part * 16;
    float a = 0.f;
#pragma unroll
    for (int cc = 0; cc < 16; ++cc)
      a += adj_emb[which * CC + c0 + cc] * We[(size_t)(c0 + cc) * 512 + col];
    a += __shfl_xor(a, 1); a += __shfl_xor(a, 2); a += __shfl_xor(a, 4);
    if (part == 0) e01[o] = a + be[col];
  } else {
    // quarter-mask scatter: block owns (cluster kc, edge-quarter part)
    int v = b - 112;
    int kc = v >> 2, part = v & 3;
    adjm[t] = 0u;
    __syncthreads();
#pragma unroll
    for (int i = 0; i < 8; ++i) {
      int base = part * 16384 + (i * 512 + t) * 4;
      int4 s4 = *(const int4*)&edge[base];
      int4 d4 = *(const int4*)&edge[EE + base];
      const int* sp = (const int*)&s4;
      const int* dp = (const int*)&d4;
#pragma unroll
      for (int e2 = 0; e2 < 4; ++e2) {
        int s = sp[e2], d = dp[e2];
        if ((s >> 7) == kc && (d >> 7) == kc)
          atomicOr(&adjm[(s & 127) * 4 + ((d & 127) >> 5)], 1u << (d & 31));
      }
    }
    __syncthreads();
    adjw4[(size_t)v * 512 + t] = adjm[t];
  }
}

// ===== fused LN1 + QKV GEMM (BK=64 x2) + rotary + attention; 52KB LDS, 3 blocks/CU ====
#define ATT_SMEM 53248
__global__ __launch_bounds__(512) void attn_kernel(const float* __restrict__ x,
                                                   const int* __restrict__ cl,
                                                   const float* __restrict__ ln1g,
                                                   const float* __restrict__ ln1b,
                                                   const float* __restrict__ Wq,
                                                   const float* __restrict__ bq,
                                                   const float* __restrict__ Wkv,
                                                   const float* __restrict__ bkv,
                                                   const unsigned* __restrict__ adjw4,
                                                   const float* __restrict__ e01,
                                                   ushort* __restrict__ AO) {
  __shared__ __align__(16) char SM[ATT_SMEM];
  ushort* Ab = (ushort*)SM;             // [128][64] per K-pass (16 KB)
  ushort* Bb = (ushort*)(SM + 16384);   // [192][64] per K-pass (24 KB)
  ushort* Qb = (ushort*)SM;             // [128][64] attn overlay
  ushort* Kb = (ushort*)(SM + 16384);   // [128][64]
  ushort* VT = (ushort*)(SM + 32768);   // [64][128]
  ushort* Pl = (ushort*)SM;             // [2][64][128] overlays Qb+Kb (after barrier)
  float* gb  = (float*)(SM + 49152);    // 256 floats; adjL overlays later
  unsigned* adjL = (unsigned*)(SM + 49152);  // 512 words
  float* e0s  = (float*)(SM + 51200);
  float* e1s  = (float*)(SM + 51456);
  float* qe0L = (float*)(SM + 51712);   // [128]
  float* qe1L = (float*)(SM + 52224);   // [128]
  float* sL   = (float*)(SM + 52736);   // [128]

  int b = blockIdx.x, t = threadIdx.x;
  int kc = b >> 3, h = b & 7;
  int w = t >> 6, l = t & 63;

  if (t < 128) gb[t] = ln1g[t];
  else if (t < 256) gb[t] = ln1b[t - 128];

  // ---- LN1 stats (once): 4 threads/row, xv kept in registers ----
  int arow_ = t >> 2, apart = t & 3;
  float xv[32];
  float mu, rs;
  {
    int srcn = cl[kc * 128 + arow_];
    const float* xr = x + (size_t)srcn * CC + apart * 32;
#pragma unroll
    for (int i = 0; i < 8; ++i) {
      float4 v4 = *(const float4*)(xr + i * 4);
      xv[i * 4 + 0] = v4.x; xv[i * 4 + 1] = v4.y; xv[i * 4 + 2] = v4.z; xv[i * 4 + 3] = v4.w;
    }
    float s = 0.f, q = 0.f;
#pragma unroll
    for (int j = 0; j < 32; ++j) { s += xv[j]; q += xv[j] * xv[j]; }
    s += __shfl_xor(s, 1); q += __shfl_xor(q, 1);
    s += __shfl_xor(s, 2); q += __shfl_xor(q, 2);
    mu = s * (1.0f / CC);
    rs = rsqrtf(q * (1.0f / CC) - mu * mu + 1e-5f);
  }
  __syncthreads();  // gb ready

  // ---- QKV GEMM: two BK=64 passes ----
  f32x4 acc[12];
#pragma unroll
  for (int nj = 0; nj < 12; ++nj) acc[nj] = (f32x4){0.f, 0.f, 0.f, 0.f};
  for (int kp = 0; kp < 2; ++kp) {
    if (t < 384) {  // B half-stage: [192][64]
      int nl = t >> 1, kh = t & 1;
      const float* bsrc; int Nw, coln;
      if (nl < 64)       { bsrc = Wq;  Nw = 512;  coln = h * 64 + nl; }
      else if (nl < 128) { bsrc = Wkv; Nw = 1024; coln = h * 64 + (nl - 64); }
      else               { bsrc = Wkv; Nw = 1024; coln = 512 + h * 64 + (nl - 128); }
#pragma unroll
      for (int kcc = 0; kcc < 4; ++kcc) {
        float vals[8];
#pragma unroll
        for (int e = 0; e < 8; ++e)
          vals[e] = bsrc[(size_t)(kp * 64 + kh * 32 + kcc * 8 + e) * Nw + coln];
        int chl = kh * 4 + kcc;
        uint4 pk;
        pk.x = (unsigned)f2bf(vals[0]) | ((unsigned)f2bf(vals[1]) << 16);
        pk.y = (unsigned)f2bf(vals[2]) | ((unsigned)f2bf(vals[3]) << 16);
        pk.z = (unsigned)f2bf(vals[4]) | ((unsigned)f2bf(vals[5]) << 16);
        pk.w = (unsigned)f2bf(vals[6]) | ((unsigned)f2bf(vals[7]) << 16);
        *(uint4*)&Bb[nl * 64 + ((chl ^ (nl & 7)) << 3)] = pk;
      }
    }
    if ((apart >> 1) == kp) {  // A half-stage: cols kp*64..+63 (parts 2kp, 2kp+1)
#pragma unroll
      for (int cc = 0; cc < 4; ++cc) {
        ushort pk8[8];
#pragma unroll
        for (int e = 0; e < 8; ++e) {
          int c = apart * 32 + cc * 8 + e;
          pk8[e] = f2bf((xv[cc * 8 + e] - mu) * rs * gb[c] + gb[128 + c]);
        }
        int chl = (apart & 1) * 4 + cc;
        uint4 pk;
        pk.x = (unsigned)pk8[0] | ((unsigned)pk8[1] << 16);
        pk.y = (unsigned)pk8[2] | ((unsigned)pk8[3] << 16);
        pk.z = (unsigned)pk8[4] | ((unsigned)pk8[5] << 16);
        pk.w = (unsigned)pk8[6] | ((unsigned)pk8[7] << 16);
        *(uint4*)&Ab[arow_ * 64 + ((chl ^ (arow_ & 7)) << 3)] = pk;
      }
    }
    __syncthreads();
#pragma unroll
    for (int kk = 0; kk < 2; ++kk) {
      int gch = kk * 4 + (l >> 4);
      int arow = w * 16 + (l & 15);
      short8 aF = *(const short8*)&Ab[arow * 64 + ((gch ^ (arow & 7)) << 3)];
#pragma unroll
      for (int nj = 0; nj < 12; ++nj) {
        int brow = nj * 16 + (l & 15);
        short8 bF = *(const short8*)&Bb[brow * 64 + ((gch ^ (brow & 7)) << 3)];
        acc[nj] = __builtin_amdgcn_mfma_f32_16x16x32_bf16(aF, bF, acc[nj], 0, 0, 0);
      }
    }
    __syncthreads();
  }

  // ---- epilogue: bias + rotary (Q,K) -> Qb/Kb ; bias -> VT ----
  {
    int mb = w * 16 + ((l >> 4) << 2);
#pragma unroll
    for (int nj = 0; nj < 8; ++nj) {
      int n = nj * 16 + (l & 15);
      int d = n & 63;
      float bias = (nj < 4) ? bq[h * 64 + d] : bkv[h * 64 + d];
      float invv = exp2f(-(float)(d >> 1) * 0.4152410118609203f);  // 10000^(-p/32)
      int ch = d >> 3;
#pragma unroll
      for (int r = 0; r < 4; ++r) {
        int m = mb + r;
        float v = acc[nj][r] + bias;
        float praw = __shfl_xor(v, 1);
        float sn, cn;
        __sincosf((float)m * invv, &sn, &cn);
        float vr = (n & 1) ? (v * cn + praw * sn) : (v * cn - praw * sn);
        ushort uv = f2bf(vr);
        if (nj < 4) Qb[m * 64 + ((ch ^ (m & 7)) << 3) + (d & 7)] = uv;
        else        Kb[m * 64 + ((ch ^ (m & 7)) << 3) + (d & 7)] = uv;
      }
    }
#pragma unroll
    for (int nj = 8; nj < 12; ++nj) {
      int n = nj * 16 + (l & 15);
      int d = n - 128;
      float bias = bkv[512 + h * 64 + d];
#pragma unroll
      for (int r = 0; r < 4; ++r) {
        int m = mb + r;
        VT[d * 128 + (((m >> 3) ^ (d & 7)) << 3) + (m & 7)] = f2bf(acc[nj][r] + bias);
      }
    }
  }
  {
    int tt5 = t & 511;
    unsigned m0q = adjw4[(size_t)(kc * 4 + 0) * 512 + tt5];
    unsigned m1q = adjw4[(size_t)(kc * 4 + 1) * 512 + tt5];
    unsigned m2q = adjw4[(size_t)(kc * 4 + 2) * 512 + tt5];
    unsigned m3q = adjw4[(size_t)(kc * 4 + 3) * 512 + tt5];
    adjL[tt5] = m0q | m1q | m2q | m3q;
  }
  if (t < 64) { e0s[t] = e01[h * 64 + t]; e1s[t] = e01[512 + h * 64 + t]; }
  __syncthreads();

  // ---- attention: two 256-thread half-units ----
  int sub = t >> 8, tt = t & 255;
  int q0 = sub * 64;
  int lw = tt >> 6;
  ushort* Plh = Pl + sub * 8192;

  {
    int row = tt >> 2, part = tt & 3;
    int gq = q0 + row;
    float a0 = 0.f, a1v = 0.f;
#pragma unroll
    for (int dd = 0; dd < 16; ++dd) {
      int d = part * 16 + dd;
      float qv = bf2f(Qb[gq * 64 + (((d >> 3) ^ (gq & 7)) << 3) + (d & 7)]);
      a0 += qv * e0s[d]; a1v += qv * e1s[d];
    }
    a0 += __shfl_xor(a0, 1); a0 += __shfl_xor(a0, 2);
    a1v += __shfl_xor(a1v, 1); a1v += __shfl_xor(a1v, 2);
    if (part == 0) { qe0L[gq] = a0; qe1L[gq] = a1v; }
  }

  int m0a = lw * 16;
  f32x4 s_acc[8];
#pragma unroll
  for (int nj = 0; nj < 8; ++nj) s_acc[nj] = (f32x4){0.f, 0.f, 0.f, 0.f};
  {
    int arow = q0 + m0a + (l & 15);
    short8 aF0 = *(const short8*)&Qb[arow * 64 + ((((l >> 4)) ^ (arow & 7)) << 3)];
    short8 aF1 = *(const short8*)&Qb[arow * 64 + (((4 + (l >> 4)) ^ (arow & 7)) << 3)];
#pragma unroll
    for (int nj = 0; nj < 8; ++nj) {
      int brow = nj * 16 + (l & 15);
      short8 b0 = *(const short8*)&Kb[brow * 64 + ((((l >> 4)) ^ (brow & 7)) << 3)];
      short8 b1v = *(const short8*)&Kb[brow * 64 + (((4 + (l >> 4)) ^ (brow & 7)) << 3)];
      s_acc[nj] = __builtin_amdgcn_mfma_f32_16x16x32_bf16(aF0, b0, s_acc[nj], 0, 0, 0);
      s_acc[nj] = __builtin_amdgcn_mfma_f32_16x16x32_bf16(aF1, b1v, s_acc[nj], 0, 0, 0);
    }
  }

  float mrow[4], ssum[4], sadj[4];
#pragma unroll
  for (int r = 0; r < 4; ++r) {
    int i = m0a + ((l >> 4) << 2) + r;
    int gi = q0 + i;
    float q0v = qe0L[gi], q1v = qe1L[gi];
    unsigned w0 = adjL[gi * 4 + 0], w1 = adjL[gi * 4 + 1], w2 = adjL[gi * 4 + 2], w3 = adjL[gi * 4 + 3];
    float mx = -1e30f;
#pragma unroll
    for (int nj = 0; nj < 8; ++nj) {
      unsigned word = (nj >> 1) == 0 ? w0 : (nj >> 1) == 1 ? w1 : (nj >> 1) == 2 ? w2 : w3;
      unsigned bit = (word >> (((nj & 1) << 4) + (l & 15))) & 1u;
      float s = (s_acc[nj][r] + (bit ? q1v : q0v)) * 0.125f;
      s_acc[nj][r] = s;
      mx = fmaxf(mx, s);
    }
    mrow[r] = mx;
  }
#pragma unroll
  for (int o = 1; o < 16; o <<= 1)
#pragma unroll
    for (int r = 0; r < 4; ++r) mrow[r] = fmaxf(mrow[r], __shfl_xor(mrow[r], o));
#pragma unroll
  for (int r = 0; r < 4; ++r) {
    float sum = 0.f;
#pragma unroll
    for (int nj = 0; nj < 8; ++nj) {
      float pv = __expf(s_acc[nj][r] - mrow[r]);
      s_acc[nj][r] = pv;
      sum += pv;
    }
    ssum[r] = sum;
  }
#pragma unroll
  for (int o = 1; o < 16; o <<= 1)
#pragma unroll
    for (int r = 0; r < 4; ++r) ssum[r] += __shfl_xor(ssum[r], o);
#pragma unroll
  for (int r = 0; r < 4; ++r) {
    int gi = q0 + m0a + ((l >> 4) << 2) + r;
    unsigned w0 = adjL[gi * 4 + 0], w1 = adjL[gi * 4 + 1], w2 = adjL[gi * 4 + 2], w3 = adjL[gi * 4 + 3];
    float inv = 1.0f / ssum[r];
    float sa = 0.f;
#pragma unroll
    for (int nj = 0; nj < 8; ++nj) {
      unsigned word = (nj >> 1) == 0 ? w0 : (nj >> 1) == 1 ? w1 : (nj >> 1) == 2 ? w2 : w3;
      unsigned bit = (word >> (((nj & 1) << 4) + (l & 15))) & 1u;
      float pv = s_acc[nj][r] * inv;
      s_acc[nj][r] = pv;
      if (bit) sa += pv;
    }
    sadj[r] = sa;
  }
#pragma unroll
  for (int o = 1; o < 16; o <<= 1)
#pragma unroll
    for (int r = 0; r < 4; ++r) sadj[r] += __shfl_xor(sadj[r], o);

  __syncthreads();  // all QK^T/qe reads of Qb/Kb complete -> safe to overlay Pl

#pragma unroll
  for (int r = 0; r < 4; ++r) {
    int i = m0a + ((l >> 4) << 2) + r;
#pragma unroll
    for (int nj = 0; nj < 8; ++nj) {
      int j = nj * 16 + (l & 15);
      Plh[i * 128 + (((j >> 3) ^ (i & 7)) << 3) + (j & 7)] = f2bf(s_acc[nj][r]);
    }
    if ((l & 15) == 0) sL[q0 + i] = sadj[r];
  }
  // (no barrier: PV reads only this wave's Plh/sL rows)

  f32x4 o_acc[4];
#pragma unroll
  for (int nj = 0; nj < 4; ++nj) o_acc[nj] = (f32x4){0.f, 0.f, 0.f, 0.f};
#pragma unroll
  for (int kk = 0; kk < 4; ++kk) {
    int prow = m0a + (l & 15);
    int ch = kk * 4 + (l >> 4);
    short8 pa = *(const short8*)&Plh[prow * 128 + ((ch ^ (prow & 7)) << 3)];
#pragma unroll
    for (int nj = 0; nj < 4; ++nj) {
      int vrow = nj * 16 + (l & 15);
      short8 vf = *(const short8*)&VT[vrow * 128 + ((ch ^ (vrow & 7)) << 3)];
      o_acc[nj] = __builtin_amdgcn_mfma_f32_16x16x32_bf16(pa, vf, o_acc[nj], 0, 0, 0);
    }
  }
#pragma unroll
  for (int nj = 0; nj < 4; ++nj)
#pragma unroll
    for (int r = 0; r < 4; ++r) {
      int i = m0a + ((l >> 4) << 2) + r;
      int d = nj * 16 + (l & 15);
      float s = sL[q0 + i];
      float v = o_acc[nj][r] + e0s[d] * (1.0f - s) + e1s[d] * s;
      float pv = __shfl_xor(v, 1);
      if ((l & 1) == 0) {
        unsigned pack = (unsigned)f2bf(v) | ((unsigned)f2bf(pv) << 16);
        *(unsigned*)&AO[(size_t)(kc * 128 + q0 + i) * 512 + h * 64 + d] = pack;
      }
    }
}

// ===== fused tail: 256 blocks x 16 rows, 512 threads, dbuf weight staging (R15) =====
__global__ __launch_bounds__(512) void tail_kernel(const ushort* __restrict__ AO,
                                                   const ushort* __restrict__ WoT,
                                                   const float* __restrict__ bo,
                                                   const ushort* __restrict__ W1T,
                                                   const float* __restrict__ b1,
                                                   const ushort* __restrict__ W2T,
                                                   const float* __restrict__ b2,
                                                   const float* __restrict__ x,
                                                   const int* __restrict__ cl,
                                                   const float* __restrict__ g1,
                                                   const float* __restrict__ g2,
                                                   const float* __restrict__ ln2g,
                                                   const float* __restrict__ ln2b,
                                                   float* __restrict__ out) {
  __shared__ __align__(16) char SM[97536];
  ushort* As = (ushort*)SM;
  ushort* Bb0 = (ushort*)(SM + 16384);
  ushort* Bb1 = (ushort*)(SM + 49152);
  float (*tld)[132] = (float(*)[132])(SM + 81920);
  ushort* y2L = (ushort*)(SM + 90368);
  float* w0g1 = (float*)(SM + 94464);
  float* w1g1 = w0g1 + 128; float* w0g2 = w0g1 + 256; float* w1g2 = w0g1 + 384;
  float* lnG = w0g1 + 512; float* lnB = w0g1 + 640;

  int b = blockIdx.x, t = threadIdx.x;
  int m0t = b * 16;
  int w = t >> 6, l = t & 63;

  if (t < 128) { w0g1[t] = g1[t] + g1[256 + t]; w1g1[t] = g1[128 + t] - g1[256 + t]; }
  else if (t < 256) { int i = t - 128; w0g2[i] = g2[i] + g2[256 + i]; w1g2[i] = g2[128 + i] - g2[256 + i]; }
  else if (t < 384) { int i = t - 256; lnG[i] = ln2g[i]; lnB[i] = ln2b[i]; }
#pragma unroll
  for (int i = 0; i < 2; ++i) {
    int c = t + i * 512;
    int r = c >> 6, ch = c & 63;
    *(uint4*)&As[r * 512 + (((ch & ~7) | ((ch ^ r) & 7)) << 3)] =
        *(const uint4*)&AO[(size_t)(m0t + r) * 512 + ch * 8];
  }
  auto stage = [&](int s, ushort* buf) {
#pragma unroll
    for (int i = 0; i < 4; ++i) {
      int c = t + i * 512;
      int r = c >> 4, kc = c & 15;
      const ushort* pp;
      if (s < 4)      pp = &WoT[(size_t)r * 512 + s * 128 + kc * 8];
      else if (s < 8) pp = &W1T[(size_t)((s - 4) * 128 + r) * 128 + kc * 8];
      else            pp = &W2T[(size_t)r * 512 + (s - 8) * 128 + kc * 8];
      *(uint4*)&buf[r * 128 + (((kc & 8) | ((kc ^ r) & 7)) << 3)] = *(const uint4*)pp;
    }
  };
  stage(0, Bb0);
  __syncthreads();

  int arow = l & 15;
  int brow = w * 16 + (l & 15);

  f32x4 aWo = (f32x4){0.f, 0.f, 0.f, 0.f};
  for (int s = 0; s < 4; ++s) {
    stage(s + 1, (s & 1) ? Bb0 : Bb1);
    ushort* buf = (s & 1) ? Bb1 : Bb0;
#pragma unroll
    for (int kk = 0; kk < 4; ++kk) {
      int gA = s * 16 + kk * 4 + (l >> 4);
      short8 aF = *(const short8*)&As[arow * 512 + (((gA & ~7) | ((gA ^ arow) & 7)) << 3)];
      int gB = kk * 4 + (l >> 4);
      short8 bF = *(const short8*)&buf[brow * 128 + (((gB & 8) | ((gB ^ brow) & 7)) << 3)];
      aWo = __builtin_amdgcn_mfma_f32_16x16x32_bf16(aF, bF, aWo, 0, 0, 0);
    }
    __syncthreads();
  }
#pragma unroll
  for (int r = 0; r < 4; ++r)
    tld[((l >> 4) << 2) + r][w * 16 + (l & 15)] = aWo[r] + bo[w * 16 + (l & 15)];
  __syncthreads();

  int row = t >> 5, part = t & 31;
  int srcn = cl[m0t + row];
  float xv[4], n1r[4];
  {
    float4 x4 = *(const float4*)(x + (size_t)srcn * CC + part * 4);
    xv[0] = x4.x; xv[1] = x4.y; xv[2] = x4.z; xv[3] = x4.w;
    float dot = 0.f;
#pragma unroll
    for (int j = 0; j < 4; ++j) { int c = part * 4 + j; dot += tld[row][c] * w0g1[c] + xv[j] * w1g1[c]; }
#pragma unroll
    for (int o = 1; o < 32; o <<= 1) dot += __shfl_xor(dot, o);
    float g = 1.0f / (1.0f + __expf(-dot));
    float s = 0.f, q = 0.f;
#pragma unroll
    for (int j = 0; j < 4; ++j) {
      int c = part * 4 + j;
      float nv = tld[row][c] * g + xv[j] * (1.0f - g);
      n1r[j] = nv; s += nv; q += nv * nv;
    }
#pragma unroll
    for (int o = 1; o < 32; o <<= 1) { s += __shfl_xor(s, o); q += __shfl_xor(q, o); }
    float mu = s * (1.0f / CC);
    float rs = rsqrtf(q * (1.0f / CC) - mu * mu + 1e-5f);
    ushort pk2[4];
#pragma unroll
    for (int j = 0; j < 4; ++j) { int c = part * 4 + j; pk2[j] = f2bf((n1r[j] - mu) * rs * lnG[c] + lnB[c]); }
    int ch = part >> 1;
    int off = (((ch & 8) | ((ch ^ row) & 7)) << 3) + (part & 1) * 4;
    uint2 u2;
    u2.x = (unsigned)pk2[0] | ((unsigned)pk2[1] << 16);
    u2.y = (unsigned)pk2[2] | ((unsigned)pk2[3] << 16);
    *(uint2*)&y2L[row * 128 + off] = u2;
  }
  __syncthreads();

  for (int s = 4; s < 8; ++s) {
    stage(s + 1, (s & 1) ? Bb0 : Bb1);
    ushort* buf = (s & 1) ? Bb1 : Bb0;
    f32x4 a1 = (f32x4){0.f, 0.f, 0.f, 0.f};
#pragma unroll
    for (int kk = 0; kk < 4; ++kk) {
      int gch = kk * 4 + (l >> 4);
      short8 aF = *(const short8*)&y2L[arow * 128 + (((gch & 8) | ((gch ^ arow) & 7)) << 3)];
      short8 bF = *(const short8*)&buf[brow * 128 + (((gch & 8) | ((gch ^ brow) & 7)) << 3)];
      a1 = __builtin_amdgcn_mfma_f32_16x16x32_bf16(aF, bF, a1, 0, 0, 0);
    }
#pragma unroll
    for (int r = 0; r < 4; ++r) {
      int rw = ((l >> 4) << 2) + r;
      int n = (s - 4) * 128 + w * 16 + (l & 15);
      float v = a1[r] + b1[n];
      v = 0.5f * v * (1.0f + erff(v * 0.70710678118654752f));
      int ch = n >> 3;
      As[rw * 512 + (((ch & ~7) | ((ch ^ rw) & 7)) << 3) + (n & 7)] = f2bf(v);
    }
    __syncthreads();
  }

  f32x4 a2 = (f32x4){0.f, 0.f, 0.f, 0.f};
  for (int s = 8; s < 12; ++s) {
    if (s < 11) stage(s + 1, (s & 1) ? Bb0 : Bb1);
    ushort* buf = (s & 1) ? Bb1 : Bb0;
#pragma unroll
    for (int kk = 0; kk < 4; ++kk) {
      int gA = (s - 8) * 16 + kk * 4 + (l >> 4);
      short8 aF = *(const short8*)&As[arow * 512 + (((gA & ~7) | ((gA ^ arow) & 7)) << 3)];
      int gB = kk * 4 + (l >> 4);
      short8 bF = *(const short8*)&buf[brow * 128 + (((gB & 8) | ((gB ^ brow) & 7)) << 3)];
      a2 = __builtin_amdgcn_mfma_f32_16x16x32_bf16(aF, bF, a2, 0, 0, 0);
    }
    __syncthreads();
  }
#pragma unroll
  for (int r = 0; r < 4; ++r)
    tld[((l >> 4) << 2) + r][w * 16 + (l & 15)] = a2[r] + b2[w * 16 + (l & 15)];
  __syncthreads();

  {
    float dot = 0.f;
#pragma unroll
    for (int j = 0; j < 4; ++j) { int c = part * 4 + j; dot += tld[row][c] * w0g2[c] + n1r[j] * w1g2[c]; }
#pragma unroll
    for (int o = 1; o < 32; o <<= 1) dot += __shfl_xor(dot, o);
    float g = 1.0f / (1.0f + __expf(-dot));
    float4 o4;
    float* op4 = (float*)&o4;
#pragma unroll
    for (int j = 0; j < 4; ++j) {
      int c = part * 4 + j;
      op4[j] = xv[j] + tld[row][c] * g + n1r[j] * (1.0f - g);
    }
    *(float4*)(out + (size_t)srcn * CC + part * 4) = o4;
  }
}

extern "C" void kernel_launch(void* const* d_in, const int* in_sizes, int n_in,
                              void* d_out, int out_size, void* d_ws, size_t ws_size,
                              hipStream_t stream) {
  const float* x       = (const float*)d_in[0];
  const int*   edge    = (const int*)d_in[1];
  const int*   clusters= (const int*)d_in[2];
  const float* adj_emb = (const float*)d_in[3];
  const float* ln1_g   = (const float*)d_in[4];
  const float* ln1_b   = (const float*)d_in[5];
  const float* Wq      = (const float*)d_in[6];
  const float* bq      = (const float*)d_in[7];
  const float* Wkv     = (const float*)d_in[8];
  const float* bkv     = (const float*)d_in[9];
  const float* We      = (const float*)d_in[10];
  const float* be      = (const float*)d_in[11];
  const float* Wo      = (const float*)d_in[12];
  const float* bo      = (const float*)d_in[13];
  const float* gate1   = (const float*)d_in[14];
  const float* ln2_g   = (const float*)d_in[15];
  const float* ln2_b   = (const float*)d_in[16];
  const float* W1      = (const float*)d_in[17];
  const float* b1      = (const float*)d_in[18];
  const float* W2      = (const float*)d_in[19];
  const float* b2      = (const float*)d_in[20];
  const float* gate2   = (const float*)d_in[21];

  char* wsb = (char*)d_ws;
  float* e01  = (float*)wsb;                         // 4 KB
  unsigned* adjw4 = (unsigned*)(wsb + 4096);         // 256 KB (fully overwritten; no memset)
  ushort* WoT = (ushort*)(wsb + 266240);             // 128 KB
  ushort* W1T = (ushort*)(wsb + 397312);             // 128 KB
  ushort* W2T = (ushort*)(wsb + 528384);             // 128 KB
  ushort* AO  = (ushort*)(wsb + 659456);             // 4 MB

  prep_kernel<<<240, 512, 0, stream>>>(Wo, W1, W2, adj_emb, We, be, edge,
                                       WoT, W1T, W2T, e01, adjw4);
  attn_kernel<<<256, 512, 0, stream>>>(x, clusters, ln1_g, ln1_b, Wq, bq, Wkv, bkv,
                                       adjw4, e01, AO);
  tail_kernel<<<256, 512, 0, stream>>>(AO, WoT, bo, W1T, b1, W2T, b2,
                                       x, clusters, gate1, gate2, ln2_g, ln2_b, (float*)d_out);
}

// Round 18
// 38.903 us; speedup vs baseline: 1.2216x; 1.0458x over previous
//
#include <hip/hip_runtime.h>
#include <math.h>

#define NNODES 4096
#define CC     128
#define EE     65536
#define MM     128

typedef __attribute__((ext_vector_type(8))) short short8;
typedef __attribute__((ext_vector_type(4))) float f32x4;

__device__ __forceinline__ float bf2f(ushort u) { return __uint_as_float(((unsigned)u) << 16); }
__device__ __forceinline__ ushort f2bf(float f) {
  unsigned b = __float_as_uint(f);
  return (ushort)((b + 0x7FFFu + ((b >> 16) & 1u)) >> 16);
}

// ===== prep (344 blocks): Wo/W1/W2 transposes (96) + Wq/Wkv->WqkvT (96) + e01 (16)
//       + rotary tables (8) + quarter-mask edge scatter (128) =====
__global__ __launch_bounds__(512) void prep_kernel(const float* __restrict__ Wo,
                                                   const float* __restrict__ W1,
                                                   const float* __restrict__ W2,
                                                   const float* __restrict__ Wq,
                                                   const float* __restrict__ Wkv,
                                                   const float* __restrict__ adj_emb,
                                                   const float* __restrict__ We,
                                                   const float* __restrict__ be,
                                                   const int* __restrict__ edge,
                                                   ushort* __restrict__ WoT,
                                                   ushort* __restrict__ W1T,
                                                   ushort* __restrict__ W2T,
                                                   ushort* __restrict__ WqkvT,
                                                   float* __restrict__ cosF,
                                                   float* __restrict__ sinF,
                                                   float* __restrict__ e01,
                                                   unsigned* __restrict__ adjw4) {
  __shared__ float lds[2][32][33];
  __shared__ unsigned adjm[512];
  int b = blockIdx.x, t = threadIdx.x;
  if (b < 192) {
    // tiled transposes: b<96 -> Wo/W1/W2 ; 96..191 -> Wq/Wkv -> WqkvT[1536][128]
    int sub = t >> 8, tt = t & 255;
    int tid = b * 2 + sub;     // 0..383
    const float* src; ushort* dst; int N, K, tile;
    if (tid < 64)        { src = Wo;  dst = WoT;             N = 128;  K = 512; tile = tid; }
    else if (tid < 128)  { src = W1;  dst = W1T;             N = 512;  K = 128; tile = tid - 64; }
    else if (tid < 192)  { src = W2;  dst = W2T;             N = 128;  K = 512; tile = tid - 128; }
    else if (tid < 256)  { src = Wq;  dst = WqkvT;           N = 512;  K = 128; tile = tid - 192; }
    else                 { src = Wkv; dst = WqkvT + 512 * 128; N = 1024; K = 128; tile = tid - 256; }
    int tilesN = N >> 5;
    int k0 = (tile / tilesN) << 5, n0 = (tile % tilesN) << 5;
#pragma unroll
    for (int i = 0; i < 4; ++i) {
      int idx = i * 256 + tt, kk = idx >> 5, nn = idx & 31;
      lds[sub][kk][nn] = src[(size_t)(k0 + kk) * N + n0 + nn];
    }
    __syncthreads();
#pragma unroll
    for (int i = 0; i < 4; ++i) {
      int idx = i * 256 + tt, nn = idx >> 5, kk = idx & 31;
      dst[(size_t)(n0 + nn) * K + k0 + kk] = f2bf(lds[sub][kk][nn]);
    }
  } else if (b < 208) {
    int gidx = (b - 192) * 512 + t;   // 0..8191
    int o = gidx >> 3, part = gidx & 7;
    int which = o >> 9, col = o & 511;
    int c0 = part * 16;
    float a = 0.f;
#pragma unroll
    for (int cc = 0; cc < 16; ++cc)
      a += adj_emb[which * CC + c0 + cc] * We[(size_t)(c0 + cc) * 512 + col];
    a += __shfl_xor(a, 1); a += __shfl_xor(a, 2); a += __shfl_xor(a, 4);
    if (part == 0) e01[o] = a + be[col];
  } else if (b < 216) {
    // rotary tables [i][d]: i=0..127, d=0..63
#pragma unroll
    for (int e = 0; e < 2; ++e) {
      int idx = (b - 208) * 1024 + e * 512 + t;  // 0..8191
      int i = idx >> 6, d = idx & 63, p = d >> 1;
      float inv = exp2f(-(float)p * 0.4152410118609203f);  // 10000^(-p/32)
      float ang = (float)i * inv;
      cosF[idx] = cosf(ang);
      sinF[idx] = sinf(ang);
    }
  } else {
    // quarter-mask scatter: block owns (cluster kc, edge-quarter part)
    int v = b - 216;
    int kc = v >> 2, part = v & 3;
    adjm[t] = 0u;
    __syncthreads();
#pragma unroll
    for (int i = 0; i < 8; ++i) {
      int base = part * 16384 + (i * 512 + t) * 4;
      int4 s4 = *(const int4*)&edge[base];
      int4 d4 = *(const int4*)&edge[EE + base];
      const int* sp = (const int*)&s4;
      const int* dp = (const int*)&d4;
#pragma unroll
      for (int e2 = 0; e2 < 4; ++e2) {
        int s = sp[e2], d = dp[e2];
        if ((s >> 7) == kc && (d >> 7) == kc)
          atomicOr(&adjm[(s & 127) * 4 + ((d & 127) >> 5)], 1u << (d & 31));
      }
    }
    __syncthreads();
    adjw4[(size_t)v * 512 + t] = adjm[t];
  }
}

// ===== fused LN1 + QKV GEMM (BK=64 x2, bf16 weights) + table rotary + attention =====
#define ATT_SMEM 53248
__global__ __launch_bounds__(512) void attn_kernel(const float* __restrict__ x,
                                                   const int* __restrict__ cl,
                                                   const float* __restrict__ ln1g,
                                                   const float* __restrict__ ln1b,
                                                   const ushort* __restrict__ WqkvT,
                                                   const float* __restrict__ bq,
                                                   const float* __restrict__ bkv,
                                                   const float* __restrict__ cosF,
                                                   const float* __restrict__ sinF,
                                                   const unsigned* __restrict__ adjw4,
                                                   const float* __restrict__ e01,
                                                   ushort* __restrict__ AO) {
  __shared__ __align__(16) char SM[ATT_SMEM];
  ushort* Ab = (ushort*)SM;             // [128][64] per K-pass (16 KB)
  ushort* Bb = (ushort*)(SM + 16384);   // [192][64] per K-pass (24 KB)
  ushort* Qb = (ushort*)SM;             // [128][64] attn overlay
  ushort* Kb = (ushort*)(SM + 16384);   // [128][64]
  ushort* VT = (ushort*)(SM + 32768);   // [64][128]
  ushort* Pl = (ushort*)SM;             // [2][64][128] overlays Qb+Kb (after barrier)
  float* gb  = (float*)(SM + 49152);    // 256 floats; adjL overlays later
  unsigned* adjL = (unsigned*)(SM + 49152);  // 512 words
  float* e0s  = (float*)(SM + 51200);
  float* e1s  = (float*)(SM + 51456);
  float* qe0L = (float*)(SM + 51712);   // [128]
  float* qe1L = (float*)(SM + 52224);   // [128]
  float* sL   = (float*)(SM + 52736);   // [128]

  int b = blockIdx.x, t = threadIdx.x;
  int kc = b >> 3, h = b & 7;
  int w = t >> 6, l = t & 63;

  if (t < 128) gb[t] = ln1g[t];
  else if (t < 256) gb[t] = ln1b[t - 128];

  // ---- LN1 stats (once): 4 threads/row, xv kept in registers ----
  int arow_ = t >> 2, apart = t & 3;
  float xv[32];
  float mu, rs;
  {
    int srcn = cl[kc * 128 + arow_];
    const float* xr = x + (size_t)srcn * CC + apart * 32;
#pragma unroll
    for (int i = 0; i < 8; ++i) {
      float4 v4 = *(const float4*)(xr + i * 4);
      xv[i * 4 + 0] = v4.x; xv[i * 4 + 1] = v4.y; xv[i * 4 + 2] = v4.z; xv[i * 4 + 3] = v4.w;
    }
    float s = 0.f, q = 0.f;
#pragma unroll
    for (int j = 0; j < 32; ++j) { s += xv[j]; q += xv[j] * xv[j]; }
    s += __shfl_xor(s, 1); q += __shfl_xor(q, 1);
    s += __shfl_xor(s, 2); q += __shfl_xor(q, 2);
    mu = s * (1.0f / CC);
    rs = rsqrtf(q * (1.0f / CC) - mu * mu + 1e-5f);
  }
  __syncthreads();  // gb ready

  // ---- QKV GEMM: two BK=64 passes (B from pre-converted WqkvT) ----
  f32x4 acc[12];
#pragma unroll
  for (int nj = 0; nj < 12; ++nj) acc[nj] = (f32x4){0.f, 0.f, 0.f, 0.f};
  for (int kp = 0; kp < 2; ++kp) {
    if (t < 384) {  // B half-stage: [192][64] bf16 copies
      int nl = t >> 1, kh = t & 1;
      int grow;
      if (nl < 64)       grow = h * 64 + nl;
      else if (nl < 128) grow = 512 + h * 64 + (nl - 64);
      else               grow = 1024 + h * 64 + (nl - 128);
      const ushort* srcp = &WqkvT[(size_t)grow * 128 + kp * 64 + kh * 32];
#pragma unroll
      for (int kcc = 0; kcc < 4; ++kcc) {
        uint4 pk = *(const uint4*)&srcp[kcc * 8];
        int chl = kh * 4 + kcc;
        *(uint4*)&Bb[nl * 64 + ((chl ^ (nl & 7)) << 3)] = pk;
      }
    }
    if ((apart >> 1) == kp) {  // A half-stage: cols kp*64..+63
#pragma unroll
      for (int cc = 0; cc < 4; ++cc) {
        ushort pk8[8];
#pragma unroll
        for (int e = 0; e < 8; ++e) {
          int c = apart * 32 + cc * 8 + e;
          pk8[e] = f2bf((xv[cc * 8 + e] - mu) * rs * gb[c] + gb[128 + c]);
        }
        int chl = (apart & 1) * 4 + cc;
        uint4 pk;
        pk.x = (unsigned)pk8[0] | ((unsigned)pk8[1] << 16);
        pk.y = (unsigned)pk8[2] | ((unsigned)pk8[3] << 16);
        pk.z = (unsigned)pk8[4] | ((unsigned)pk8[5] << 16);
        pk.w = (unsigned)pk8[6] | ((unsigned)pk8[7] << 16);
        *(uint4*)&Ab[arow_ * 64 + ((chl ^ (arow_ & 7)) << 3)] = pk;
      }
    }
    __syncthreads();
#pragma unroll
    for (int kk = 0; kk < 2; ++kk) {
      int gch = kk * 4 + (l >> 4);
      int arow = w * 16 + (l & 15);
      short8 aF = *(const short8*)&Ab[arow * 64 + ((gch ^ (arow & 7)) << 3)];
#pragma unroll
      for (int nj = 0; nj < 12; ++nj) {
        int brow = nj * 16 + (l & 15);
        short8 bF = *(const short8*)&Bb[brow * 64 + ((gch ^ (brow & 7)) << 3)];
        acc[nj] = __builtin_amdgcn_mfma_f32_16x16x32_bf16(aF, bF, acc[nj], 0, 0, 0);
      }
    }
    __syncthreads();
  }

  // ---- epilogue: bias + table rotary (Q,K) -> Qb/Kb ; bias -> VT ----
  {
    int mb = w * 16 + ((l >> 4) << 2);
#pragma unroll
    for (int nj = 0; nj < 8; ++nj) {
      int n = nj * 16 + (l & 15);
      int d = n & 63;
      float bias = (nj < 4) ? bq[h * 64 + d] : bkv[h * 64 + d];
      int ch = d >> 3;
#pragma unroll
      for (int r = 0; r < 4; ++r) {
        int m = mb + r;
        float v = acc[nj][r] + bias;
        float praw = __shfl_xor(v, 1);
        float cv = cosF[m * 64 + d], sv = sinF[m * 64 + d];
        float vr = (n & 1) ? (v * cv + praw * sv) : (v * cv - praw * sv);
        ushort uv = f2bf(vr);
        if (nj < 4) Qb[m * 64 + ((ch ^ (m & 7)) << 3) + (d & 7)] = uv;
        else        Kb[m * 64 + ((ch ^ (m & 7)) << 3) + (d & 7)] = uv;
      }
    }
#pragma unroll
    for (int nj = 8; nj < 12; ++nj) {
      int n = nj * 16 + (l & 15);
      int d = n - 128;
      float bias = bkv[512 + h * 64 + d];
#pragma unroll
      for (int r = 0; r < 4; ++r) {
        int m = mb + r;
        VT[d * 128 + (((m >> 3) ^ (d & 7)) << 3) + (m & 7)] = f2bf(acc[nj][r] + bias);
      }
    }
  }
  {
    int tt5 = t & 511;
    unsigned m0q = adjw4[(size_t)(kc * 4 + 0) * 512 + tt5];
    unsigned m1q = adjw4[(size_t)(kc * 4 + 1) * 512 + tt5];
    unsigned m2q = adjw4[(size_t)(kc * 4 + 2) * 512 + tt5];
    unsigned m3q = adjw4[(size_t)(kc * 4 + 3) * 512 + tt5];
    adjL[tt5] = m0q | m1q | m2q | m3q;
  }
  if (t < 64) { e0s[t] = e01[h * 64 + t]; e1s[t] = e01[512 + h * 64 + t]; }
  __syncthreads();

  // ---- attention: two 256-thread half-units ----
  int sub = t >> 8, tt = t & 255;
  int q0 = sub * 64;
  int lw = tt >> 6;
  ushort* Plh = Pl + sub * 8192;

  {
    int row = tt >> 2, part = tt & 3;
    int gq = q0 + row;
    float a0 = 0.f, a1v = 0.f;
#pragma unroll
    for (int dd = 0; dd < 16; ++dd) {
      int d = part * 16 + dd;
      float qv = bf2f(Qb[gq * 64 + (((d >> 3) ^ (gq & 7)) << 3) + (d & 7)]);
      a0 += qv * e0s[d]; a1v += qv * e1s[d];
    }
    a0 += __shfl_xor(a0, 1); a0 += __shfl_xor(a0, 2);
    a1v += __shfl_xor(a1v, 1); a1v += __shfl_xor(a1v, 2);
    if (part == 0) { qe0L[gq] = a0; qe1L[gq] = a1v; }
  }

  int m0a = lw * 16;
  f32x4 s_acc[8];
#pragma unroll
  for (int nj = 0; nj < 8; ++nj) s_acc[nj] = (f32x4){0.f, 0.f, 0.f, 0.f};
  {
    int arow = q0 + m0a + (l & 15);
    short8 aF0 = *(const short8*)&Qb[arow * 64 + ((((l >> 4)) ^ (arow & 7)) << 3)];
    short8 aF1 = *(const short8*)&Qb[arow * 64 + (((4 + (l >> 4)) ^ (arow & 7)) << 3)];
#pragma unroll
    for (int nj = 0; nj < 8; ++nj) {
      int brow = nj * 16 + (l & 15);
      short8 b0 = *(const short8*)&Kb[brow * 64 + ((((l >> 4)) ^ (brow & 7)) << 3)];
      short8 b1v = *(const short8*)&Kb[brow * 64 + (((4 + (l >> 4)) ^ (brow & 7)) << 3)];
      s_acc[nj] = __builtin_amdgcn_mfma_f32_16x16x32_bf16(aF0, b0, s_acc[nj], 0, 0, 0);
      s_acc[nj] = __builtin_amdgcn_mfma_f32_16x16x32_bf16(aF1, b1v, s_acc[nj], 0, 0, 0);
    }
  }

  float mrow[4], ssum[4], sadj[4];
#pragma unroll
  for (int r = 0; r < 4; ++r) {
    int i = m0a + ((l >> 4) << 2) + r;
    int gi = q0 + i;
    float q0v = qe0L[gi], q1v = qe1L[gi];
    unsigned w0 = adjL[gi * 4 + 0], w1 = adjL[gi * 4 + 1], w2 = adjL[gi * 4 + 2], w3 = adjL[gi * 4 + 3];
    float mx = -1e30f;
#pragma unroll
    for (int nj = 0; nj < 8; ++nj) {
      unsigned word = (nj >> 1) == 0 ? w0 : (nj >> 1) == 1 ? w1 : (nj >> 1) == 2 ? w2 : w3;
      unsigned bit = (word >> (((nj & 1) << 4) + (l & 15))) & 1u;
      float s = (s_acc[nj][r] + (bit ? q1v : q0v)) * 0.125f;
      s_acc[nj][r] = s;
      mx = fmaxf(mx, s);
    }
    mrow[r] = mx;
  }
#pragma unroll
  for (int o = 1; o < 16; o <<= 1)
#pragma unroll
    for (int r = 0; r < 4; ++r) mrow[r] = fmaxf(mrow[r], __shfl_xor(mrow[r], o));
#pragma unroll
  for (int r = 0; r < 4; ++r) {
    float sum = 0.f;
#pragma unroll
    for (int nj = 0; nj < 8; ++nj) {
      float pv = __expf(s_acc[nj][r] - mrow[r]);
      s_acc[nj][r] = pv;
      sum += pv;
    }
    ssum[r] = sum;
  }
#pragma unroll
  for (int o = 1; o < 16; o <<= 1)
#pragma unroll
    for (int r = 0; r < 4; ++r) ssum[r] += __shfl_xor(ssum[r], o);
#pragma unroll
  for (int r = 0; r < 4; ++r) {
    int gi = q0 + m0a + ((l >> 4) << 2) + r;
    unsigned w0 = adjL[gi * 4 + 0], w1 = adjL[gi * 4 + 1], w2 = adjL[gi * 4 + 2], w3 = adjL[gi * 4 + 3];
    float inv = 1.0f / ssum[r];
    float sa = 0.f;
#pragma unroll
    for (int nj = 0; nj < 8; ++nj) {
      unsigned word = (nj >> 1) == 0 ? w0 : (nj >> 1) == 1 ? w1 : (nj >> 1) == 2 ? w2 : w3;
      unsigned bit = (word >> (((nj & 1) << 4) + (l & 15))) & 1u;
      float pv = s_acc[nj][r] * inv;
      s_acc[nj][r] = pv;
      if (bit) sa += pv;
    }
    sadj[r] = sa;
  }
#pragma unroll
  for (int o = 1; o < 16; o <<= 1)
#pragma unroll
    for (int r = 0; r < 4; ++r) sadj[r] += __shfl_xor(sadj[r], o);

  __syncthreads();  // all QK^T/qe reads of Qb/Kb complete -> safe to overlay Pl

#pragma unroll
  for (int r = 0; r < 4; ++r) {
    int i = m0a + ((l >> 4) << 2) + r;
#pragma unroll
    for (int nj = 0; nj < 8; ++nj) {
      int j = nj * 16 + (l & 15);
      Plh[i * 128 + (((j >> 3) ^ (i & 7)) << 3) + (j & 7)] = f2bf(s_acc[nj][r]);
    }
    if ((l & 15) == 0) sL[q0 + i] = sadj[r];
  }
  // (no barrier: PV reads only this wave's Plh/sL rows)

  f32x4 o_acc[4];
#pragma unroll
  for (int nj = 0; nj < 4; ++nj) o_acc[nj] = (f32x4){0.f, 0.f, 0.f, 0.f};
#pragma unroll
  for (int kk = 0; kk < 4; ++kk) {
    int prow = m0a + (l & 15);
    int ch = kk * 4 + (l >> 4);
    short8 pa = *(const short8*)&Plh[prow * 128 + ((ch ^ (prow & 7)) << 3)];
#pragma unroll
    for (int nj = 0; nj < 4; ++nj) {
      int vrow = nj * 16 + (l & 15);
      short8 vf = *(const short8*)&VT[vrow * 128 + ((ch ^ (vrow & 7)) << 3)];
      o_acc[nj] = __builtin_amdgcn_mfma_f32_16x16x32_bf16(pa, vf, o_acc[nj], 0, 0, 0);
    }
  }
#pragma unroll
  for (int nj = 0; nj < 4; ++nj)
#pragma unroll
    for (int r = 0; r < 4; ++r) {
      int i = m0a + ((l >> 4) << 2) + r;
      int d = nj * 16 + (l & 15);
      float s = sL[q0 + i];
      float v = o_acc[nj][r] + e0s[d] * (1.0f - s) + e1s[d] * s;
      float pv = __shfl_xor(v, 1);
      if ((l & 1) == 0) {
        unsigned pack = (unsigned)f2bf(v) | ((unsigned)f2bf(pv) << 16);
        *(unsigned*)&AO[(size_t)(kc * 128 + q0 + i) * 512 + h * 64 + d] = pack;
      }
    }
}

// ===== fused tail: 256 blocks x 16 rows, 512 threads, dbuf weight staging =====
__global__ __launch_bounds__(512) void tail_kernel(const ushort* __restrict__ AO,
                                                   const ushort* __restrict__ WoT,
                                                   const float* __restrict__ bo,
                                                   const ushort* __restrict__ W1T,
                                                   const float* __restrict__ b1,
                                                   const ushort* __restrict__ W2T,
                                                   const float* __restrict__ b2,
                                                   const float* __restrict__ x,
                                                   const int* __restrict__ cl,
                                                   const float* __restrict__ g1,
                                                   const float* __restrict__ g2,
                                                   const float* __restrict__ ln2g,
                                                   const float* __restrict__ ln2b,
                                                   float* __restrict__ out) {
  __shared__ __align__(16) char SM[97536];
  ushort* As = (ushort*)SM;
  ushort* Bb0 = (ushort*)(SM + 16384);
  ushort* Bb1 = (ushort*)(SM + 49152);
  float (*tld)[132] = (float(*)[132])(SM + 81920);
  ushort* y2L = (ushort*)(SM + 90368);
  float* w0g1 = (float*)(SM + 94464);
  float* w1g1 = w0g1 + 128; float* w0g2 = w0g1 + 256; float* w1g2 = w0g1 + 384;
  float* lnG = w0g1 + 512; float* lnB = w0g1 + 640;

  int b = blockIdx.x, t = threadIdx.x;
  int m0t = b * 16;
  int w = t >> 6, l = t & 63;

  if (t < 128) { w0g1[t] = g1[t] + g1[256 + t]; w1g1[t] = g1[128 + t] - g1[256 + t]; }
  else if (t < 256) { int i = t - 128; w0g2[i] = g2[i] + g2[256 + i]; w1g2[i] = g2[128 + i] - g2[256 + i]; }
  else if (t < 384) { int i = t - 256; lnG[i] = ln2g[i]; lnB[i] = ln2b[i]; }
#pragma unroll
  for (int i = 0; i < 2; ++i) {
    int c = t + i * 512;
    int r = c >> 6, ch = c & 63;
    *(uint4*)&As[r * 512 + (((ch & ~7) | ((ch ^ r) & 7)) << 3)] =
        *(const uint4*)&AO[(size_t)(m0t + r) * 512 + ch * 8];
  }
  auto stage = [&](int s, ushort* buf) {
#pragma unroll
    for (int i = 0; i < 4; ++i) {
      int c = t + i * 512;
      int r = c >> 4, kc = c & 15;
      const ushort* pp;
      if (s < 4)      pp = &WoT[(size_t)r * 512 + s * 128 + kc * 8];
      else if (s < 8) pp = &W1T[(size_t)((s - 4) * 128 + r) * 128 + kc * 8];
      else            pp = &W2T[(size_t)r * 512 + (s - 8) * 128 + kc * 8];
      *(uint4*)&buf[r * 128 + (((kc & 8) | ((kc ^ r) & 7)) << 3)] = *(const uint4*)pp;
    }
  };
  stage(0, Bb0);
  __syncthreads();

  int arow = l & 15;
  int brow = w * 16 + (l & 15);

  f32x4 aWo = (f32x4){0.f, 0.f, 0.f, 0.f};
  for (int s = 0; s < 4; ++s) {
    stage(s + 1, (s & 1) ? Bb0 : Bb1);
    ushort* buf = (s & 1) ? Bb1 : Bb0;
#pragma unroll
    for (int kk = 0; kk < 4; ++kk) {
      int gA = s * 16 + kk * 4 + (l >> 4);
      short8 aF = *(const short8*)&As[arow * 512 + (((gA & ~7) | ((gA ^ arow) & 7)) << 3)];
      int gB = kk * 4 + (l >> 4);
      short8 bF = *(const short8*)&buf[brow * 128 + (((gB & 8) | ((gB ^ brow) & 7)) << 3)];
      aWo = __builtin_amdgcn_mfma_f32_16x16x32_bf16(aF, bF, aWo, 0, 0, 0);
    }
    __syncthreads();
  }
#pragma unroll
  for (int r = 0; r < 4; ++r)
    tld[((l >> 4) << 2) + r][w * 16 + (l & 15)] = aWo[r] + bo[w * 16 + (l & 15)];
  __syncthreads();

  int row = t >> 5, part = t & 31;
  int srcn = cl[m0t + row];
  float xv[4], n1r[4];
  {
    float4 x4 = *(const float4*)(x + (size_t)srcn * CC + part * 4);
    xv[0] = x4.x; xv[1] = x4.y; xv[2] = x4.z; xv[3] = x4.w;
    float dot = 0.f;
#pragma unroll
    for (int j = 0; j < 4; ++j) { int c = part * 4 + j; dot += tld[row][c] * w0g1[c] + xv[j] * w1g1[c]; }
#pragma unroll
    for (int o = 1; o < 32; o <<= 1) dot += __shfl_xor(dot, o);
    float g = 1.0f / (1.0f + __expf(-dot));
    float s = 0.f, q = 0.f;
#pragma unroll
    for (int j = 0; j < 4; ++j) {
      int c = part * 4 + j;
      float nv = tld[row][c] * g + xv[j] * (1.0f - g);
      n1r[j] = nv; s += nv; q += nv * nv;
    }
#pragma unroll
    for (int o = 1; o < 32; o <<= 1) { s += __shfl_xor(s, o); q += __shfl_xor(q, o); }
    float mu = s * (1.0f / CC);
    float rs = rsqrtf(q * (1.0f / CC) - mu * mu + 1e-5f);
    ushort pk2[4];
#pragma unroll
    for (int j = 0; j < 4; ++j) { int c = part * 4 + j; pk2[j] = f2bf((n1r[j] - mu) * rs * lnG[c] + lnB[c]); }
    int ch = part >> 1;
    int off = (((ch & 8) | ((ch ^ row) & 7)) << 3) + (part & 1) * 4;
    uint2 u2;
    u2.x = (unsigned)pk2[0] | ((unsigned)pk2[1] << 16);
    u2.y = (unsigned)pk2[2] | ((unsigned)pk2[3] << 16);
    *(uint2*)&y2L[row * 128 + off] = u2;
  }
  __syncthreads();

  for (int s = 4; s < 8; ++s) {
    stage(s + 1, (s & 1) ? Bb0 : Bb1);
    ushort* buf = (s & 1) ? Bb1 : Bb0;
    f32x4 a1 = (f32x4){0.f, 0.f, 0.f, 0.f};
#pragma unroll
    for (int kk = 0; kk < 4; ++kk) {
      int gch = kk * 4 + (l >> 4);
      short8 aF = *(const short8*)&y2L[arow * 128 + (((gch & 8) | ((gch ^ arow) & 7)) << 3)];
      short8 bF = *(const short8*)&buf[brow * 128 + (((gch & 8) | ((gch ^ brow) & 7)) << 3)];
      a1 = __builtin_amdgcn_mfma_f32_16x16x32_bf16(aF, bF, a1, 0, 0, 0);
    }
#pragma unroll
    for (int r = 0; r < 4; ++r) {
      int rw = ((l >> 4) << 2) + r;
      int n = (s - 4) * 128 + w * 16 + (l & 15);
      float v = a1[r] + b1[n];
      v = 0.5f * v * (1.0f + erff(v * 0.70710678118654752f));
      int ch = n >> 3;
      As[rw * 512 + (((ch & ~7) | ((ch ^ rw) & 7)) << 3) + (n & 7)] = f2bf(v);
    }
    __syncthreads();
  }

  f32x4 a2 = (f32x4){0.f, 0.f, 0.f, 0.f};
  for (int s = 8; s < 12; ++s) {
    if (s < 11) stage(s + 1, (s & 1) ? Bb0 : Bb1);
    ushort* buf = (s & 1) ? Bb1 : Bb0;
#pragma unroll
    for (int kk = 0; kk < 4; ++kk) {
      int gA = (s - 8) * 16 + kk * 4 + (l >> 4);
      short8 aF = *(const short8*)&As[arow * 512 + (((gA & ~7) | ((gA ^ arow) & 7)) << 3)];
      int gB = kk * 4 + (l >> 4);
      short8 bF = *(const short8*)&buf[brow * 128 + (((gB & 8) | ((gB ^ brow) & 7)) << 3)];
      a2 = __builtin_amdgcn_mfma_f32_16x16x32_bf16(aF, bF, a2, 0, 0, 0);
    }
    __syncthreads();
  }
#pragma unroll
  for (int r = 0; r < 4; ++r)
    tld[((l >> 4) << 2) + r][w * 16 + (l & 15)] = a2[r] + b2[w * 16 + (l & 15)];
  __syncthreads();

  {
    float dot = 0.f;
#pragma unroll
    for (int j = 0; j < 4; ++j) { int c = part * 4 + j; dot += tld[row][c] * w0g2[c] + n1r[j] * w1g2[c]; }
#pragma unroll
    for (int o = 1; o < 32; o <<= 1) dot += __shfl_xor(dot, o);
    float g = 1.0f / (1.0f + __expf(-dot));
    float4 o4;
    float* op4 = (float*)&o4;
#pragma unroll
    for (int j = 0; j < 4; ++j) {
      int c = part * 4 + j;
      op4[j] = xv[j] + tld[row][c] * g + n1r[j] * (1.0f - g);
    }
    *(float4*)(out + (size_t)srcn * CC + part * 4) = o4;
  }
}

extern "C" void kernel_launch(void* const* d_in, const int* in_sizes, int n_in,
                              void* d_out, int out_size, void* d_ws, size_t ws_size,
                              hipStream_t stream) {
  const float* x       = (const float*)d_in[0];
  const int*   edge    = (const int*)d_in[1];
  const int*   clusters= (const int*)d_in[2];
  const float* adj_emb = (const float*)d_in[3];
  const float* ln1_g   = (const float*)d_in[4];
  const float* ln1_b   = (const float*)d_in[5];
  const float* Wq      = (const float*)d_in[6];
  const float* bq      = (const float*)d_in[7];
  const float* Wkv     = (const float*)d_in[8];
  const float* bkv     = (const float*)d_in[9];
  const float* We      = (const float*)d_in[10];
  const float* be      = (const float*)d_in[11];
  const float* Wo      = (const float*)d_in[12];
  const float* bo      = (const float*)d_in[13];
  const float* gate1   = (const float*)d_in[14];
  const float* ln2_g   = (const float*)d_in[15];
  const float* ln2_b   = (const float*)d_in[16];
  const float* W1      = (const float*)d_in[17];
  const float* b1      = (const float*)d_in[18];
  const float* W2      = (const float*)d_in[19];
  const float* b2      = (const float*)d_in[20];
  const float* gate2   = (const float*)d_in[21];

  char* wsb = (char*)d_ws;
  float* e01  = (float*)wsb;                         // 4 KB
  unsigned* adjw4 = (unsigned*)(wsb + 4096);         // 256 KB (fully overwritten; no memset)
  ushort* WoT = (ushort*)(wsb + 266240);             // 128 KB
  ushort* W1T = (ushort*)(wsb + 397312);             // 128 KB
  ushort* W2T = (ushort*)(wsb + 528384);             // 128 KB
  ushort* WqkvT = (ushort*)(wsb + 659456);           // 384 KB
  float* cosF = (float*)(wsb + 1052672);             // 32 KB
  float* sinF = (float*)(wsb + 1085440);             // 32 KB
  ushort* AO  = (ushort*)(wsb + 1118208);            // 4 MB

  prep_kernel<<<344, 512, 0, stream>>>(Wo, W1, W2, Wq, Wkv, adj_emb, We, be, edge,
                                       WoT, W1T, W2T, WqkvT, cosF, sinF, e01, adjw4);
  attn_kernel<<<256, 512, 0, stream>>>(x, clusters, ln1_g, ln1_b, WqkvT, bq, bkv,
                                       cosF, sinF, adjw4, e01, AO);
  tail_kernel<<<256, 512, 0, stream>>>(AO, WoT, bo, W1T, b1, W2T, b2,
                                       x, clusters, gate1, gate2, ln2_g, ln2_b, (float*)d_out);
}